// Round 2
// baseline (476.148 us; speedup 1.0000x reference)
//
#include <hip/hip_runtime.h>
#include <hip/hip_bf16.h>
#include <math.h>

// Workspace layout (bytes) — max footprint 984,064 B (unchanged).
//   xb  : [4][1024][112] bf16  @ 0        (917,504)  conv input (fv | fv_max)
//   fo  : [4][1024]      f32   @ 917504   ( 16,384)  feat_o (written by k_pool)
//   sw  : [4][64][49]    f32   @ 933888   ( 50,176)  slice weights
// Launch graph: k_pool -> k_conv -> k_tail   (3 launches, was 7).
#define XB_OFF 0
#define FO_OFF 917504
#define SW_OFF 933888

// ---------------------------------------------------------------------------
// K1: pool + argmax + feat_o, one block per (b,c), 4 waves x 28 maps.
// Each 16-lane group reduces one 16x16 map (4 maps per wave-instruction, four
// contiguous 256B segments -> fully-used cachelines). All 112 m meet in-block:
// argmax keys stay in exact fp32 (np.argmax first-occurrence via strict > over
// ascending m), so no atomics, no init pass, and feat_o is written here in
// fp32 (exact fv[argmax] semantics, better than the old bf16-rounded path).
// LDS staging arrays are u32-typed (4B-aligned by construction) and only
// WRITTEN through a bf16 view — the u32 readout reinterpret is always aligned.
__global__ __launch_bounds__(256) void k_pool(const float* __restrict__ oct,
                                              __hip_bfloat16* __restrict__ xb,
                                              float* __restrict__ fo) {
    __shared__ unsigned int fvu[56];    // 112 bf16 fv values
    __shared__ unsigned int fvmu[56];   // 112 bf16 fv_max values
    __shared__ float s_bmx[4], s_bat[4], s_bfv[4];
    __shared__ int   s_bm[4];
    __hip_bfloat16* fvl  = (__hip_bfloat16*)fvu;
    __hip_bfloat16* fvml = (__hip_bfloat16*)fvmu;
    int b = blockIdx.x >> 9, c = blockIdx.x & 511;
    int t = threadIdx.x, w = t >> 6, lane = t & 63;
    int g = lane >> 4, p = lane & 15;
    const float* base = oct + ((size_t)b * 112 * 512 + c) * 256;
    float bmx = -INFINITY, bat = 0.f, bfv = -INFINITY;
    int bm = 0;
    for (int it = 0; it < 7; ++it) {
        int m = w * 28 + it * 4 + g;
        const float4* mp = (const float4*)(base + (size_t)m * (512 * 256));
        float4 a0 = mp[p];
        float4 a1 = mp[p + 16];
        float4 a2 = mp[p + 32];
        float4 a3 = mp[p + 48];
        float s = (a0.x + a0.y + a0.z + a0.w) + (a1.x + a1.y + a1.z + a1.w)
                + (a2.x + a2.y + a2.z + a2.w) + (a3.x + a3.y + a3.z + a3.w);
        float mx = fmaxf(fmaxf(fmaxf(a0.x, a0.y), fmaxf(a0.z, a0.w)),
                         fmaxf(fmaxf(a1.x, a1.y), fmaxf(a1.z, a1.w)));
        mx = fmaxf(mx, fmaxf(fmaxf(fmaxf(a2.x, a2.y), fmaxf(a2.z, a2.w)),
                             fmaxf(fmaxf(a3.x, a3.y), fmaxf(a3.z, a3.w))));
#pragma unroll
        for (int off = 1; off <= 8; off <<= 1) {
            s  += __shfl_xor(s, off);
            mx  = fmaxf(mx, __shfl_xor(mx, off));
        }
        float fv = s * (1.0f / 256.0f);
        if (mx > bmx) { bmx = mx; bm = m; bat = fv; }   // ascending m: strict > == first occurrence
        bfv = fmaxf(bfv, fv);
        if (p == 0) {
            fvl[m]  = __float2bfloat16(fv);
            fvml[m] = __float2bfloat16(mx);
        }
    }
    // merge the 4 groups within the wave (value, then smaller-m tie-break)
#pragma unroll
    for (int off = 16; off <= 32; off <<= 1) {
        float omx = __shfl_xor(bmx, off);
        int   om  = __shfl_xor(bm, off);
        float oat = __shfl_xor(bat, off);
        float obf = __shfl_xor(bfv, off);
        if (omx > bmx || (omx == bmx && om < bm)) { bmx = omx; bm = om; bat = oat; }
        bfv = fmaxf(bfv, obf);
    }
    if (lane == 0) { s_bmx[w] = bmx; s_bm[w] = bm; s_bat[w] = bat; s_bfv[w] = bfv; }
    __syncthreads();
    if (t == 0) {
        float M = s_bmx[0], A = s_bat[0], F = s_bfv[0];
        int   I = s_bm[0];
        for (int w2 = 1; w2 < 4; ++w2) {   // waves cover ascending m: strict > keeps first
            if (s_bmx[w2] > M || (s_bmx[w2] == M && s_bm[w2] < I)) {
                M = s_bmx[w2]; I = s_bm[w2]; A = s_bat[w2];
            }
            F = fmaxf(F, s_bfv[w2]);
        }
        fo[b * 1024 + c]       = F;   // feat_o_avg = max_m fv  (fp32 exact)
        fo[b * 1024 + 512 + c] = A;   // feat_o_max = fv at argmax_m fv_max
    }
    // coalesced bf16 row writeout (u32 stores)
    unsigned int* xo  = (unsigned int*)(xb + (size_t)(b * 1024 + c) * 112);
    unsigned int* xo2 = (unsigned int*)(xb + (size_t)(b * 1024 + 512 + c) * 112);
    if (t < 56)                    xo[t]       = fvu[t];
    else if (t >= 64 && t < 120)   xo2[t - 64] = fvmu[t - 64];
}

// ---------------------------------------------------------------------------
// K3: conv1d (Cin=1024, K=64, L=112 -> 49) — UNCHANGED from proven version.
__global__ __launch_bounds__(256) void k_conv(const __hip_bfloat16* __restrict__ xb,
                                              const float* __restrict__ w1,
                                              const float* __restrict__ b1,
                                              float* __restrict__ sw) {
    __shared__ unsigned int xs[256 * 61];   // 62,464 B
    __shared__ float red[4][25];
    int bx = blockIdx.x;
    int lh = bx & 1, co = (bx >> 1) & 63, b = bx >> 7;
    int t = threadIdx.x, wv = t >> 6, lane = t & 63;
    int l0u = lh * 12;                      // uint offset of window start (bf16 l0=24*lh)
    float acc[25];
#pragma unroll
    for (int i = 0; i < 25; i++) acc[i] = 0.f;
    const unsigned int* gxb = (const unsigned int*)xb;
    for (int chunk = 0; chunk < 4; chunk++) {
        __syncthreads();
        for (int r = wv; r < 256; r += 4)
            if (lane < 56)
                xs[r * 61 + lane] = gxb[((size_t)b * 1024 + chunk * 256 + r) * 56 + lane];
        __syncthreads();
        int cil = wv * 64 + lane;
        int ci  = chunk * 256 + cil;
        const unsigned int* xu = xs + cil * 61 + l0u;
        float xf[88];
#pragma unroll
        for (int i = 0; i < 44; i++) {
            unsigned int u = xu[i];
            xf[2 * i]     = __uint_as_float(u << 16);
            xf[2 * i + 1] = __uint_as_float(u & 0xffff0000u);
        }
        const float* wrow = w1 + ((size_t)co * 1024 + ci) * 64;
#pragma unroll
        for (int kc = 0; kc < 4; kc++) {
            float ww[16];
#pragma unroll
            for (int j = 0; j < 16; j++) ww[j] = wrow[kc * 16 + j];
#pragma unroll
            for (int k = 0; k < 16; k++)
#pragma unroll
                for (int i = 0; i < 25; i++)
                    acc[i] += ww[k] * xf[kc * 16 + k + i];
        }
    }
#pragma unroll
    for (int i = 0; i < 25; i++) {
#pragma unroll
        for (int off = 32; off >= 1; off >>= 1)
            acc[i] += __shfl_xor(acc[i], off);
    }
    if (lane < 25) red[wv][lane] = acc[lane];
    __syncthreads();
    if (t < 25) {
        float s = red[0][t] + red[1][t] + red[2][t] + red[3][t] + b1[co];
        float sg = 1.f / (1.f + expf(-s));
        int l = lh * 24 + t;                // lh=0: 0..24; lh=1: 24..48 (24 dup-dropped)
        if (!(lh == 1 && t == 0))
            sw[(size_t)(b * 64 + co) * 49 + l] = sg;
    }
}

// ---------------------------------------------------------------------------
// K4: fused tail: convf+sigmoid -> rf (LDS), feat_f (LDS), head. One block/b.
__global__ __launch_bounds__(256) void k_tail(const float* __restrict__ sw,
                                              const float* __restrict__ cw,
                                              const float* __restrict__ cb,
                                              const float* __restrict__ ff,
                                              const float* __restrict__ fo,
                                              const float* __restrict__ hw,
                                              const float* __restrict__ hb,
                                              float* __restrict__ out) {
    __shared__ float swl[3136];
    __shared__ float cwl[4160];
    __shared__ float rfl[169];
    __shared__ float ffl[512];
    __shared__ float hred[3][4];
    int b = blockIdx.x, t = threadIdx.x, w = t >> 6, lane = t & 63;
    for (int i = t; i < 3136; i += 256) swl[i] = sw[b * 3136 + i];
    for (int i = t; i < 4160; i += 256) cwl[i] = cw[i];
    __syncthreads();
    // convf (K=5, stride=4, pad=2) -> 1 + sigmoid
    if (t < 169) {
        int o = t / 13, l = t % 13;
        float s = cb[o];
        for (int i = 0; i < 64; i++) {
#pragma unroll
            for (int k = 0; k < 5; k++) {
                int pos = 4 * l + k - 2;
                if (pos >= 0 && pos < 49)
                    s += swl[i * 49 + pos] * cwl[(o * 64 + i) * 5 + k];
            }
        }
        rfl[t] = 1.f + 1.f / (1.f + expf(-s));
    }
    __syncthreads();
    // feat_f: thread t owns channels t and t+256; rfl reads broadcast (uniform).
    {
        float acc1 = 0.f, acc2 = 0.f;
        const float* r1 = ff + ((size_t)b * 512 + t) * 169;
        const float* r2 = r1 + 256 * 169;
        for (int pidx = 0; pidx < 169; ++pidx) {
            float rv = rfl[pidx];
            acc1 += r1[pidx] * rv;
            acc2 += r2[pidx] * rv;
        }
        ffl[t]       = acc1 * (1.0f / 169.0f);
        ffl[t + 256] = acc2 * (1.0f / 169.0f);
    }
    __syncthreads();
    // head Linear(1536 -> 3); feat = [ffl(512) | fo(1024)]
    {
        float s0 = 0.f, s1 = 0.f, s2 = 0.f;
#pragma unroll
        for (int rep = 0; rep < 6; ++rep) {
            int i = rep * 256 + t;
            float fv = (i < 512) ? ffl[i] : fo[b * 1024 + (i - 512)];
            s0 += fv * hw[i];
            s1 += fv * hw[1536 + i];
            s2 += fv * hw[3072 + i];
        }
#pragma unroll
        for (int off = 32; off >= 1; off >>= 1) {
            s0 += __shfl_xor(s0, off);
            s1 += __shfl_xor(s1, off);
            s2 += __shfl_xor(s2, off);
        }
        if (lane == 0) { hred[0][w] = s0; hred[1][w] = s1; hred[2][w] = s2; }
    }
    __syncthreads();
    if (t < 3)
        out[b * 3 + t] = hred[t][0] + hred[t][1] + hred[t][2] + hred[t][3] + hb[t];
}

// ---------------------------------------------------------------------------
extern "C" void kernel_launch(void* const* d_in, const int* in_sizes, int n_in,
                              void* d_out, int out_size, void* d_ws, size_t ws_size,
                              hipStream_t stream) {
    const float* ff  = (const float*)d_in[0];  // features_f [4,512,13,13]
    const float* oct = (const float*)d_in[1];  // oct_feats  [4,112,512,16,16]
    const float* w1  = (const float*)d_in[2];  // conv1d_w   [64,1024,64]
    const float* b1  = (const float*)d_in[3];  // conv1d_b   [64]
    const float* cw  = (const float*)d_in[4];  // convf_w    [13,64,5]
    const float* cb  = (const float*)d_in[5];  // convf_b    [13]
    const float* hw  = (const float*)d_in[6];  // head_w     [3,1536]
    const float* hb  = (const float*)d_in[7];  // head_b     [3]
    float* out = (float*)d_out;                // [4,3]
    char* ws = (char*)d_ws;
    __hip_bfloat16* xb = (__hip_bfloat16*)(ws + XB_OFF);
    float*          fo = (float*)(ws + FO_OFF);
    float*          sw = (float*)(ws + SW_OFF);

    hipLaunchKernelGGL(k_pool, dim3(2048), dim3(256), 0, stream, oct, xb, fo);
    hipLaunchKernelGGL(k_conv, dim3(512),  dim3(256), 0, stream, xb, w1, b1, sw);
    hipLaunchKernelGGL(k_tail, dim3(4),    dim3(256), 0, stream, sw, cw, cb, ff, fo, hw, hb, out);
}

// Round 4
// 466.588 us; speedup vs baseline: 1.0205x; 1.0205x over previous
//
#include <hip/hip_runtime.h>
#include <hip/hip_bf16.h>
#include <math.h>

// Workspace layout (bytes). Proven-safe footprint is 984,064 B. The spill
// region (fvx/fva) is used ONLY if ws_size says it exists (runtime branch in
// kernel_launch) — otherwise the proven atomic-keyed argmax path runs.
//   xb  : [4][1024][112] bf16 @ 0        (917,504)  conv input (fv | fv_max)
//   fo  : [4][1024]      f32  @ 917504   ( 16,384)  feat_o
//   am  : [4][512]       u64  @ 933888   ( 16,384)  argmax keys (fallback; dead before sw)
//   sw  : [4][64][49]    f32  @ 933888   ( 50,176)  slice weights (after am dead)
//   fvx : [4][512][112]  f32  @ 984064   (917,504)  fp32 fv_max keys   (spill path only)
//   fva : [4][512][112]  f32  @ 1901568  (917,504)  fp32 fv payload    (spill path only)
#define XB_OFF  0
#define FO_OFF  917504
#define AM_OFF  933888
#define SW_OFF  933888
#define FVX_OFF 984064
#define FVA_OFF 1901568
#define SPILL_NEED (FVA_OFF + 917504)

// ---------------------------------------------------------------------------
// Spill path K1a: streaming pool — wave per (b,m,c) map, pure linear HBM
// stream (wave n reads the n-th contiguous 1 KB map). No atomics; fp32
// sums/maxes spilled to fvx/fva for the tiny exact-argmax pass.
__global__ __launch_bounds__(256) void k_pool1(const float* __restrict__ oct,
                                               __hip_bfloat16* __restrict__ xb,
                                               float* __restrict__ fvx,
                                               float* __restrict__ fva) {
    int wg = (blockIdx.x * 256 + threadIdx.x) >> 6;   // (b*112+m)*512+c
    int lane = threadIdx.x & 63;
    const float4* p = (const float4*)(oct + (size_t)wg * 256);
    float4 v = p[lane];
    float s  = v.x + v.y + v.z + v.w;
    float mx = fmaxf(fmaxf(v.x, v.y), fmaxf(v.z, v.w));
#pragma unroll
    for (int off = 32; off >= 1; off >>= 1) {
        s  += __shfl_xor(s, off);
        mx  = fmaxf(mx, __shfl_xor(mx, off));
    }
    if (lane == 0) {
        int c  = wg & 511;
        int bm = wg >> 9;
        int m  = bm % 112;
        int b  = bm / 112;
        float fv = s * (1.0f / 256.0f);
        xb[((size_t)b * 1024 + c) * 112 + m]       = __float2bfloat16(fv);
        xb[((size_t)b * 1024 + 512 + c) * 112 + m] = __float2bfloat16(mx);
        fvx[((size_t)b * 512 + c) * 112 + m] = mx;
        fva[((size_t)b * 512 + c) * 112 + m] = fv;
    }
}

// Spill path K1b: exact-fp32 argmax + feat_o. Wave per (b,c); 1.8 MB
// cache-resident. np.argmax first-occurrence: strict > over ascending m;
// butterfly ties break toward smaller m.
__global__ __launch_bounds__(256) void k_pool2(const float* __restrict__ fvx,
                                               const float* __restrict__ fva,
                                               float* __restrict__ fo) {
    int wid  = blockIdx.x * 4 + (threadIdx.x >> 6);   // b*512+c
    int lane = threadIdx.x & 63;
    int b = wid >> 9, c = wid & 511;
    const float* kx = fvx + (size_t)wid * 112;
    const float* va = fva + (size_t)wid * 112;
    int m0 = lane, m1 = lane + 64;
    float k0 = (m0 < 112) ? kx[m0] : -INFINITY;
    float k1 = (m1 < 112) ? kx[m1] : -INFINITY;
    float f0 = (m0 < 112) ? va[m0] : -INFINITY;
    float f1 = (m1 < 112) ? va[m1] : -INFINITY;
    float bk; int bm;
    if (k1 > k0) { bk = k1; bm = m1; } else { bk = k0; bm = m0; }
    float bf = fmaxf(f0, f1);
#pragma unroll
    for (int off = 32; off >= 1; off >>= 1) {
        float ok = __shfl_xor(bk, off);
        int   om = __shfl_xor(bm, off);
        if (ok > bk || (ok == bk && om < bm)) { bk = ok; bm = om; }
        bf = fmaxf(bf, __shfl_xor(bf, off));
    }
    if (lane == 0) {
        fo[b * 1024 + c]       = bf;      // feat_o_avg = max_m fv (fp32 exact)
        fo[b * 1024 + 512 + c] = va[bm];  // feat_o_max = fv at argmax_m fv_max
    }
}

// ---------------------------------------------------------------------------
// Fallback path (proven baseline): K0 zero keys, K1 atomic packed-key pool,
// K2 feat_o gather. Byte-identical logic to the 466 µs baseline.
__global__ __launch_bounds__(256) void k_init(unsigned long long* __restrict__ am) {
    am[blockIdx.x * 256 + threadIdx.x] = 0ULL;
}

__global__ __launch_bounds__(256) void k_pool(const float* __restrict__ oct,
                                              __hip_bfloat16* __restrict__ xb,
                                              unsigned long long* __restrict__ am) {
    int wg = (blockIdx.x * 256 + threadIdx.x) >> 6;   // (b*112+m)*512+c
    int lane = threadIdx.x & 63;
    const float4* p = (const float4*)(oct + (size_t)wg * 256);
    float4 v = p[lane];
    float s  = v.x + v.y + v.z + v.w;
    float mx = fmaxf(fmaxf(v.x, v.y), fmaxf(v.z, v.w));
#pragma unroll
    for (int off = 32; off >= 1; off >>= 1) {
        s  += __shfl_xor(s, off);
        mx  = fmaxf(mx, __shfl_xor(mx, off));
    }
    if (lane == 0) {
        int c  = wg & 511;
        int bm = wg >> 9;
        int m  = bm % 112;
        int b  = bm / 112;
        xb[((size_t)b * 1024 + c) * 112 + m]       = __float2bfloat16(s * (1.0f / 256.0f));
        xb[((size_t)b * 1024 + 512 + c) * 112 + m] = __float2bfloat16(mx);
        unsigned int u = __float_as_uint(mx);
        unsigned int key = (u & 0x80000000u) ? ~u : (u | 0x80000000u);
        unsigned long long pk = ((unsigned long long)key << 32) | (unsigned int)(111 - m);
        atomicMax(&am[b * 512 + c], pk);
    }
}

__global__ __launch_bounds__(256) void k_feato(const __hip_bfloat16* __restrict__ xb,
                                               const unsigned long long* __restrict__ am,
                                               float* __restrict__ fo) {
    int wid  = blockIdx.x * 4 + (threadIdx.x >> 6);   // b*512+c
    int lane = threadIdx.x & 63;
    int b = wid >> 9, c = wid & 511;
    const __hip_bfloat16* fvrow = xb + ((size_t)b * 1024 + c) * 112;
    float v0 = (lane < 112)      ? __bfloat162float(fvrow[lane])      : -INFINITY;
    float v1 = (lane + 64 < 112) ? __bfloat162float(fvrow[lane + 64]) : -INFINITY;
    float mxf = fmaxf(v0, v1);
#pragma unroll
    for (int off = 32; off >= 1; off >>= 1)
        mxf = fmaxf(mxf, __shfl_xor(mxf, off));
    if (lane == 0) {
        int mstar = 111 - (int)(unsigned int)(am[b * 512 + c] & 0xFFFFFFFFULL);
        fo[b * 1024 + c]       = mxf;
        fo[b * 1024 + 512 + c] = __bfloat162float(fvrow[mstar]);
    }
}

// ---------------------------------------------------------------------------
// K3: conv1d (Cin=1024, K=64, L=112 -> 49) — UNCHANGED proven version.
__global__ __launch_bounds__(256) void k_conv(const __hip_bfloat16* __restrict__ xb,
                                              const float* __restrict__ w1,
                                              const float* __restrict__ b1,
                                              float* __restrict__ sw) {
    __shared__ unsigned int xs[256 * 61];   // 62,464 B
    __shared__ float red[4][25];
    int bx = blockIdx.x;
    int lh = bx & 1, co = (bx >> 1) & 63, b = bx >> 7;
    int t = threadIdx.x, wv = t >> 6, lane = t & 63;
    int l0u = lh * 12;                      // uint offset of window start (bf16 l0=24*lh)
    float acc[25];
#pragma unroll
    for (int i = 0; i < 25; i++) acc[i] = 0.f;
    const unsigned int* gxb = (const unsigned int*)xb;
    for (int chunk = 0; chunk < 4; chunk++) {
        __syncthreads();
        for (int r = wv; r < 256; r += 4)
            if (lane < 56)
                xs[r * 61 + lane] = gxb[((size_t)b * 1024 + chunk * 256 + r) * 56 + lane];
        __syncthreads();
        int cil = wv * 64 + lane;
        int ci  = chunk * 256 + cil;
        const unsigned int* xu = xs + cil * 61 + l0u;
        float xf[88];
#pragma unroll
        for (int i = 0; i < 44; i++) {
            unsigned int u = xu[i];
            xf[2 * i]     = __uint_as_float(u << 16);
            xf[2 * i + 1] = __uint_as_float(u & 0xffff0000u);
        }
        const float* wrow = w1 + ((size_t)co * 1024 + ci) * 64;
#pragma unroll
        for (int kc = 0; kc < 4; kc++) {
            float ww[16];
#pragma unroll
            for (int j = 0; j < 16; j++) ww[j] = wrow[kc * 16 + j];
#pragma unroll
            for (int k = 0; k < 16; k++)
#pragma unroll
                for (int i = 0; i < 25; i++)
                    acc[i] += ww[k] * xf[kc * 16 + k + i];
        }
    }
#pragma unroll
    for (int i = 0; i < 25; i++) {
#pragma unroll
        for (int off = 32; off >= 1; off >>= 1)
            acc[i] += __shfl_xor(acc[i], off);
    }
    if (lane < 25) red[wv][lane] = acc[lane];
    __syncthreads();
    if (t < 25) {
        float s = red[0][t] + red[1][t] + red[2][t] + red[3][t] + b1[co];
        float sg = 1.f / (1.f + expf(-s));
        int l = lh * 24 + t;                // lh=0: 0..24; lh=1: 24..48 (24 dup-dropped)
        if (!(lh == 1 && t == 0))
            sw[(size_t)(b * 64 + co) * 49 + l] = sg;
    }
}

// ---------------------------------------------------------------------------
// K4: fused tail: convf+sigmoid -> rf (LDS), feat_f (LDS), head. One block/b.
// UNCHANGED from round-2 version that passed.
__global__ __launch_bounds__(256) void k_tail(const float* __restrict__ sw,
                                              const float* __restrict__ cw,
                                              const float* __restrict__ cb,
                                              const float* __restrict__ ff,
                                              const float* __restrict__ fo,
                                              const float* __restrict__ hw,
                                              const float* __restrict__ hb,
                                              float* __restrict__ out) {
    __shared__ float swl[3136];
    __shared__ float cwl[4160];
    __shared__ float rfl[169];
    __shared__ float ffl[512];
    __shared__ float hred[3][4];
    int b = blockIdx.x, t = threadIdx.x, w = t >> 6, lane = t & 63;
    for (int i = t; i < 3136; i += 256) swl[i] = sw[b * 3136 + i];
    for (int i = t; i < 4160; i += 256) cwl[i] = cw[i];
    __syncthreads();
    // convf (K=5, stride=4, pad=2) -> 1 + sigmoid
    if (t < 169) {
        int o = t / 13, l = t % 13;
        float s = cb[o];
        for (int i = 0; i < 64; i++) {
#pragma unroll
            for (int k = 0; k < 5; k++) {
                int pos = 4 * l + k - 2;
                if (pos >= 0 && pos < 49)
                    s += swl[i * 49 + pos] * cwl[(o * 64 + i) * 5 + k];
            }
        }
        rfl[t] = 1.f + 1.f / (1.f + expf(-s));
    }
    __syncthreads();
    // feat_f: thread t owns channels t and t+256; rfl reads broadcast (uniform).
    {
        float acc1 = 0.f, acc2 = 0.f;
        const float* r1 = ff + ((size_t)b * 512 + t) * 169;
        const float* r2 = r1 + 256 * 169;
        for (int pidx = 0; pidx < 169; ++pidx) {
            float rv = rfl[pidx];
            acc1 += r1[pidx] * rv;
            acc2 += r2[pidx] * rv;
        }
        ffl[t]       = acc1 * (1.0f / 169.0f);
        ffl[t + 256] = acc2 * (1.0f / 169.0f);
    }
    __syncthreads();
    // head Linear(1536 -> 3); feat = [ffl(512) | fo(1024)]
    {
        float s0 = 0.f, s1 = 0.f, s2 = 0.f;
#pragma unroll
        for (int rep = 0; rep < 6; ++rep) {
            int i = rep * 256 + t;
            float fv = (i < 512) ? ffl[i] : fo[b * 1024 + (i - 512)];
            s0 += fv * hw[i];
            s1 += fv * hw[1536 + i];
            s2 += fv * hw[3072 + i];
        }
#pragma unroll
        for (int off = 32; off >= 1; off >>= 1) {
            s0 += __shfl_xor(s0, off);
            s1 += __shfl_xor(s1, off);
            s2 += __shfl_xor(s2, off);
        }
        if (lane == 0) { hred[0][w] = s0; hred[1][w] = s1; hred[2][w] = s2; }
    }
    __syncthreads();
    if (t < 3)
        out[b * 3 + t] = hred[t][0] + hred[t][1] + hred[t][2] + hred[t][3] + hb[t];
}

// ---------------------------------------------------------------------------
extern "C" void kernel_launch(void* const* d_in, const int* in_sizes, int n_in,
                              void* d_out, int out_size, void* d_ws, size_t ws_size,
                              hipStream_t stream) {
    const float* ff  = (const float*)d_in[0];  // features_f [4,512,13,13]
    const float* oct = (const float*)d_in[1];  // oct_feats  [4,112,512,16,16]
    const float* w1  = (const float*)d_in[2];  // conv1d_w   [64,1024,64]
    const float* b1  = (const float*)d_in[3];  // conv1d_b   [64]
    const float* cw  = (const float*)d_in[4];  // convf_w    [13,64,5]
    const float* cb  = (const float*)d_in[5];  // convf_b    [13]
    const float* hw  = (const float*)d_in[6];  // head_w     [3,1536]
    const float* hb  = (const float*)d_in[7];  // head_b     [3]
    float* out = (float*)d_out;                // [4,3]
    char* ws = (char*)d_ws;
    __hip_bfloat16*     xb = (__hip_bfloat16*)(ws + XB_OFF);
    float*              fo = (float*)(ws + FO_OFF);
    unsigned long long* am = (unsigned long long*)(ws + AM_OFF);
    float*              sw = (float*)(ws + SW_OFF);

    if (ws_size >= (size_t)SPILL_NEED) {
        // exact-fp32 argmax path (no atomics, no init pass)
        float* fvx = (float*)(ws + FVX_OFF);
        float* fva = (float*)(ws + FVA_OFF);
        hipLaunchKernelGGL(k_pool1, dim3(57344), dim3(256), 0, stream, oct, xb, fvx, fva);
        hipLaunchKernelGGL(k_pool2, dim3(512),   dim3(256), 0, stream, fvx, fva, fo);
    } else {
        // proven baseline path within the 984,064 B footprint
        hipLaunchKernelGGL(k_init,  dim3(8),     dim3(256), 0, stream, am);
        hipLaunchKernelGGL(k_pool,  dim3(57344), dim3(256), 0, stream, oct, xb, am);
        hipLaunchKernelGGL(k_feato, dim3(512),   dim3(256), 0, stream, xb, am, fo);
    }
    hipLaunchKernelGGL(k_conv, dim3(512), dim3(256), 0, stream, xb, w1, b1, sw);
    hipLaunchKernelGGL(k_tail, dim3(4),   dim3(256), 0, stream, sw, cw, cb, ff, fo, hw, hb, out);
}